// Round 1
// baseline (91.587 us; speedup 1.0000x reference)
//
#include <hip/hip_runtime.h>
#include <cstdint>

#define NBIN 128
#define NREP 4            // one LDS histogram replica per wave (256 thr = 4 waves)

// CONST1 = (2*pi*4)^-0.5 ; CONST2 = 8 -> exponent scale = -1/8
#define CONST1F 0.19947114020071635f

__global__ __launch_bounds__(256) void kde_hist_kernel(
    const float* __restrict__ images, const float* __restrict__ masks,
    float* __restrict__ ws_p, float* __restrict__ ws_msum,
    int B, int C, int P, int chunks, int chunk_size)
{
    __shared__ float s_hist[NREP][NBIN];
    __shared__ float s_ms[NREP];

    const int tid = threadIdx.x;
    const int wv  = tid >> 6;

    const int blk   = blockIdx.x;
    const int chunk = blk % chunks;
    const int bc    = blk / chunks;
    const int b     = bc / C;
    const int c     = bc - b * C;

    for (int i = tid; i < NREP * NBIN; i += 256)
        ((float*)s_hist)[i] = 0.0f;
    __syncthreads();

    const float step     = 255.0f / 127.0f;   // color grid spacing
    const float inv_step = 127.0f / 255.0f;
    const float D        = 10.0f;             // exp(-D^2/8)=3.7e-6; worst-case p err ~7e-7 << 8.85e-5

    const int pstart = chunk * chunk_size;
    const int pend   = min(P, pstart + chunk_size);
    const float* img = images + (size_t)bc * P;
    const float* msk = masks  + (size_t)b  * P;   // mask has 1 channel, shared across C

    float msum_local = 0.0f;
    for (int p = pstart + tid; p < pend; p += 256) {
        const float m = msk[p];
        if (c == 0) msum_local += m;          // count mask once per batch (c==0 blocks only)
        if (m != 0.0f) {
            const float x = img[p];
            int jlo = (int)ceilf((x - D) * inv_step);
            int jhi = (int)floorf((x + D) * inv_step);
            jlo = max(jlo, 0);
            jhi = min(jhi, NBIN - 1);
            // trip count ~11 for every lane -> near-uniform, little divergence
            for (int j = jlo; j <= jhi; ++j) {
                const float d = fmaf((float)j, -step, x);   // x - colors[j]
                const float e = __expf(d * d * -0.125f) * m;
                atomicAdd(&s_hist[wv][j], e);               // ds_add_f32
            }
        }
    }
    __syncthreads();

    // reduce the 4 wave-replicas, one global atomic per bin per block
    for (int j = tid; j < NBIN; j += 256) {
        const float v = s_hist[0][j] + s_hist[1][j] + s_hist[2][j] + s_hist[3][j];
        if (v != 0.0f) atomicAdd(&ws_p[(size_t)bc * NBIN + j], v);
    }

    if (c == 0) {
        #pragma unroll
        for (int off = 32; off > 0; off >>= 1)
            msum_local += __shfl_down(msum_local, off, 64);
        if ((tid & 63) == 0) s_ms[wv] = msum_local;
        __syncthreads();
        if (tid == 0)
            atomicAdd(&ws_msum[b], s_ms[0] + s_ms[1] + s_ms[2] + s_ms[3]);
    }
}

__global__ void kde_norm_kernel(const float* __restrict__ ws_p,
                                const float* __restrict__ ws_msum,
                                float* __restrict__ out, int C, int total)
{
    const int i = blockIdx.x * blockDim.x + threadIdx.x;
    if (i >= total) return;
    const int b = i / (C * NBIN);
    const float ms = ws_msum[b];
    const float v  = ws_p[i] * CONST1F;
    // reference: p/denom where denom!=0 else p (unnormalized sum; 0 when no mask)
    out[i] = (ms != 0.0f) ? (v / ms) : v;
}

extern "C" void kernel_launch(void* const* d_in, const int* in_sizes, int n_in,
                              void* d_out, int out_size, void* d_ws, size_t ws_size,
                              hipStream_t stream)
{
    const float* images = (const float*)d_in[0];
    const float* masks  = (const float*)d_in[1];
    // d_in[2] (colors) is an exact uniform grid; recomputed arithmetically in-kernel.

    const int C = in_sizes[0] / in_sizes[1];     // 3
    const int B = out_size / (C * NBIN);         // 8
    const int P = in_sizes[1] / B;               // 50176

    float* ws_p    = (float*)d_ws;               // B*C*NBIN unnormalized sums
    float* ws_msum = ws_p + (size_t)B * C * NBIN;

    // d_ws is re-poisoned 0xAA before every timed call -> zero our accumulators
    hipMemsetAsync(d_ws, 0, ((size_t)B * C * NBIN + B) * sizeof(float), stream);

    const int chunks = 32;                       // 8*3*32 = 768 blocks = ~12 waves/CU
    const int chunk_size = (P + chunks - 1) / chunks;
    kde_hist_kernel<<<dim3(B * C * chunks), 256, 0, stream>>>(
        images, masks, ws_p, ws_msum, B, C, P, chunks, chunk_size);

    const int total = B * C * NBIN;
    kde_norm_kernel<<<dim3((total + 255) / 256), 256, 0, stream>>>(
        ws_p, ws_msum, (float*)d_out, C, total);
}